// Round 1
// baseline (43795.312 us; speedup 1.0000x reference)
//
#include <hip/hip_runtime.h>

typedef unsigned long long ull;
typedef unsigned int uint;

#define NB 32
#define NFEAT 196
#define SEQL 64
#define ED 1024
#define HD 1024
#define VOC 32000
#define NCOMB 260                  // NFEAT + SEQL
#define NROWS (NB*NCOMB)           // 8320

#define DOT4(acc, wv, xv) acc = fmaf((wv).x,(xv).x, fmaf((wv).y,(xv).y, fmaf((wv).z,(xv).z, fmaf((wv).w,(xv).w,(acc)))))

__device__ __forceinline__ uint enc_f32(float f) {
    uint u = __float_as_uint(f);
    return (u & 0x80000000u) ? ~u : (u | 0x80000000u);
}
__device__ __forceinline__ ull shflxor64(ull v, int m) {
    uint lo = __shfl_xor((uint)v, m);
    uint hi = __shfl_xor((uint)(v >> 32), m);
    return (((ull)hi) << 32) | (ull)lo;
}

// ---------------------------------------------------------------------------
// 1) Build combined = [features ; emb[captions]]  (8320 x 1024) into ws,
//    and zero outputs[:, 0, :] (harness does not re-poison between replays).
// ---------------------------------------------------------------------------
__global__ void __launch_bounds__(256) k_build(
    const float* __restrict__ features, const int* __restrict__ captions,
    const float* __restrict__ emb, float* __restrict__ combined,
    float* __restrict__ out)
{
    const int bid = blockIdx.x;
    const int t = threadIdx.x;
    if (bid < NROWS) {
        const int b = bid / NCOMB;
        const int i = bid - b*NCOMB;
        const float* src = (i < NFEAT)
            ? (features + ((size_t)(b*NFEAT + i))*ED)
            : (emb + (size_t)captions[b*SEQL + (i - NFEAT)]*ED);
        float4* dst4 = (float4*)(combined + (size_t)bid*ED);
        const float4* s4 = (const float4*)src;
        dst4[t] = s4[t];
    } else {
        const int z = bid - NROWS;           // 0..999
        const int m = z*1024 + t*4;          // < 1,024,000 exactly covered
        if (m < NB*VOC) {
            const int b = m / VOC;
            const int v = m - b*VOC;
            float4 zz = make_float4(0.f,0.f,0.f,0.f);
            *(float4*)(out + (size_t)b*((size_t)SEQL*VOC) + v) = zz;
        }
    }
}

// ---------------------------------------------------------------------------
// 2) Attention GEMM: T = combined @ Wa1^T, fused tanh(+ba1)*Wa2 column
//    reduction -> deterministic per-(row, coltile) partial scores.
//    Tiles 64x64, K-chunks of 32, transposed LDS tiles for b128 reads.
// ---------------------------------------------------------------------------
__global__ void __launch_bounds__(256) k_attn_gemm(
    const float* __restrict__ combined, const float* __restrict__ Wa1,
    const float* __restrict__ ba1, const float* __restrict__ Wa2,
    float* __restrict__ partials)
{
    __shared__ float cs_t[32][68];
    __shared__ float wt_t[32][68];
    __shared__ float red[64][17];
    const int bid = blockIdx.x;
    const int ct = bid & 15;          // col tile 0..15
    const int rt = bid >> 4;          // row tile 0..129
    const int t = threadIdx.x;
    const int tx = t & 15, ty = t >> 4;
    const int row0 = rt*64, col0 = ct*64;

    float acc[4][4];
#pragma unroll
    for (int i = 0; i < 4; ++i)
#pragma unroll
        for (int j = 0; j < 4; ++j) acc[i][j] = 0.f;

    for (int kc = 0; kc < ED; kc += 32) {
#pragma unroll
        for (int u = 0; u < 8; ++u) {
            const int idx = t + u*256;        // 0..2047
            const int r = idx >> 5, k = idx & 31;
            cs_t[k][r] = combined[(size_t)(row0 + r)*ED + kc + k];
            wt_t[k][r] = Wa1[(size_t)(col0 + r)*ED + kc + k];
        }
        __syncthreads();
#pragma unroll
        for (int kk = 0; kk < 32; ++kk) {
            const float4 av = *(const float4*)&cs_t[kk][ty*4];
            const float4 bv = *(const float4*)&wt_t[kk][tx*4];
            acc[0][0] = fmaf(av.x, bv.x, acc[0][0]);
            acc[0][1] = fmaf(av.x, bv.y, acc[0][1]);
            acc[0][2] = fmaf(av.x, bv.z, acc[0][2]);
            acc[0][3] = fmaf(av.x, bv.w, acc[0][3]);
            acc[1][0] = fmaf(av.y, bv.x, acc[1][0]);
            acc[1][1] = fmaf(av.y, bv.y, acc[1][1]);
            acc[1][2] = fmaf(av.y, bv.z, acc[1][2]);
            acc[1][3] = fmaf(av.y, bv.w, acc[1][3]);
            acc[2][0] = fmaf(av.z, bv.x, acc[2][0]);
            acc[2][1] = fmaf(av.z, bv.y, acc[2][1]);
            acc[2][2] = fmaf(av.z, bv.z, acc[2][2]);
            acc[2][3] = fmaf(av.z, bv.w, acc[2][3]);
            acc[3][0] = fmaf(av.w, bv.x, acc[3][0]);
            acc[3][1] = fmaf(av.w, bv.y, acc[3][1]);
            acc[3][2] = fmaf(av.w, bv.z, acc[3][2]);
            acc[3][3] = fmaf(av.w, bv.w, acc[3][3]);
        }
        __syncthreads();
    }
    // epilogue: p_i = sum_j tanh(acc + ba1[col]) * Wa2[col]
#pragma unroll
    for (int i = 0; i < 4; ++i) {
        float s = 0.f;
#pragma unroll
        for (int j = 0; j < 4; ++j) {
            const int c = col0 + tx*4 + j;
            s += tanhf(acc[i][j] + ba1[c]) * Wa2[c];
        }
        red[ty*4 + i][tx] = s;
    }
    __syncthreads();
    if (t < 64) {
        float s = 0.f;
#pragma unroll
        for (int x = 0; x < 16; ++x) s += red[t][x];   // fixed order: deterministic
        partials[(size_t)(row0 + t)*16 + ct] = s;
    }
}

// ---------------------------------------------------------------------------
// 3) Per-batch softmax over 260 scores -> A (output), h0 = sum A_i*combined_i,
//    init h buffer / context / argmax slot parity 0 with captions[:,0].
// ---------------------------------------------------------------------------
__global__ void __launch_bounds__(256) k_attn_finish(
    const float* __restrict__ partials, const float* __restrict__ combined,
    const int* __restrict__ captions,
    float* __restrict__ A_out, float* __restrict__ h0,
    float* __restrict__ ctx, ull* __restrict__ slots0)
{
    const int b = blockIdx.x, t = threadIdx.x;
    __shared__ float sc[NCOMB];
    __shared__ float red[256];

    for (int i = t; i < NCOMB; i += 256) {
        float s = 0.f;
        const float* pr = partials + (size_t)(b*NCOMB + i)*16;
#pragma unroll
        for (int g = 0; g < 16; ++g) s += pr[g];
        sc[i] = s;
    }
    __syncthreads();
    float m = -1e30f;
    for (int i = t; i < NCOMB; i += 256) m = fmaxf(m, sc[i]);
    red[t] = m; __syncthreads();
    for (int s2 = 128; s2 > 0; s2 >>= 1) {
        if (t < s2) red[t] = fmaxf(red[t], red[t+s2]);
        __syncthreads();
    }
    m = red[0]; __syncthreads();
    float ssum = 0.f;
    for (int i = t; i < NCOMB; i += 256) { float e = expf(sc[i] - m); sc[i] = e; ssum += e; }
    red[t] = ssum; __syncthreads();
    for (int s2 = 128; s2 > 0; s2 >>= 1) {
        if (t < s2) red[t] += red[t+s2];
        __syncthreads();
    }
    const float S = red[0]; __syncthreads();
    for (int i = t; i < NCOMB; i += 256) {
        const float a = sc[i] / S;
        sc[i] = a;
        A_out[b*NCOMB + i] = a;
    }
    __syncthreads();
    for (int e = t; e < HD; e += 256) {
        float acc = 0.f;
        const float* cb = combined + (size_t)b*NCOMB*ED + e;
        for (int i = 0; i < NCOMB; ++i) acc = fmaf(sc[i], cb[(size_t)i*ED], acc);
        h0[(size_t)b*HD + e] = acc;
        ctx[(size_t)b*HD + e] = acc;
    }
    if (t == 0) {
        slots0[0*NB + b] = (ull)(~(uint)captions[b*SEQL]);   // decodes to captions[b,0]
#pragma unroll
        for (int g = 1; g < 8; ++g) slots0[g*NB + b] = 0ull;
    }
}

// ---------------------------------------------------------------------------
// 4) GRU cell, one kernel per step. Block j owns gate triple (j, H+j, 2H+j).
//    Wave = (j, batch-group of 8); lanes split K; butterfly reduce.
//    Also decodes prev word from argmax slots and resets current-parity slots.
// ---------------------------------------------------------------------------
__global__ void __launch_bounds__(256) k_gru(
    const float* __restrict__ emb, const float* __restrict__ ctx,
    const float* __restrict__ W_ih, const float* __restrict__ W_hh,
    const float* __restrict__ b_ih, const float* __restrict__ b_hh,
    const float* __restrict__ h_prev, float* __restrict__ h_next,
    const ull* __restrict__ slots_prev, ull* __restrict__ slots_cur)
{
    __shared__ int word_s[NB];
    const int t = threadIdx.x;
    if (t < NB) {
        ull best = 0ull;
#pragma unroll
        for (int g = 0; g < 8; ++g) {
            ull k = slots_prev[g*NB + t];
            best = (k > best) ? k : best;
        }
        word_s[t] = (int)(~(uint)best);
    }
    if (blockIdx.x == 0) slots_cur[t] = 0ull;   // 256 = 8*32 entries
    __syncthreads();

    const int j = blockIdx.x;            // 0..1023
    const int w = t >> 6, l = t & 63;
    const int b0 = w*8;

    float a[4][8];                       // 0:r(i+h) 1:z(i+h) 2:inn 3:hn
#pragma unroll
    for (int g = 0; g < 4; ++g)
#pragma unroll
        for (int i = 0; i < 8; ++i) a[g][i] = 0.f;

    const float* Wr = W_ih + (size_t)j*(ED+HD);
    const float* Wz = W_ih + (size_t)(HD + j)*(ED+HD);
    const float* Wn = W_ih + (size_t)(2*HD + j)*(ED+HD);
#pragma unroll
    for (int q = 0; q < 8; ++q) {
        const int k = q*256 + l*4;
        const float4 wr = *(const float4*)(Wr + k);
        const float4 wz = *(const float4*)(Wz + k);
        const float4 wn = *(const float4*)(Wn + k);
#pragma unroll
        for (int i = 0; i < 8; ++i) {
            const int b = b0 + i;
            const float* xs = (q < 4) ? (emb + (size_t)word_s[b]*ED + k)
                                      : (ctx + (size_t)b*HD + (k - ED));
            const float4 xv = *(const float4*)xs;
            DOT4(a[0][i], wr, xv);
            DOT4(a[1][i], wz, xv);
            DOT4(a[2][i], wn, xv);
        }
    }
    const float* Ur = W_hh + (size_t)j*HD;
    const float* Uz = W_hh + (size_t)(HD + j)*HD;
    const float* Un = W_hh + (size_t)(2*HD + j)*HD;
#pragma unroll
    for (int q = 0; q < 4; ++q) {
        const int k = q*256 + l*4;
        const float4 ur = *(const float4*)(Ur + k);
        const float4 uz = *(const float4*)(Uz + k);
        const float4 un = *(const float4*)(Un + k);
#pragma unroll
        for (int i = 0; i < 8; ++i) {
            const int b = b0 + i;
            const float4 hv = *(const float4*)(h_prev + (size_t)b*HD + k);
            DOT4(a[0][i], ur, hv);
            DOT4(a[1][i], uz, hv);
            DOT4(a[3][i], un, hv);
        }
    }
    // butterfly reduce 4x8 over 64 lanes (halve batch idx, then fold)
    int s = (l >> 5) & 1;
    int ib = s*4;
    float tA[4][4];
#pragma unroll
    for (int g = 0; g < 4; ++g)
#pragma unroll
        for (int ii = 0; ii < 4; ++ii) {
            const float send = a[g][(1^s)*4 + ii];
            tA[g][ii] = a[g][s*4 + ii] + __shfl_xor(send, 32);
        }
    s = (l >> 4) & 1; ib += s*2;
    float tB[4][2];
#pragma unroll
    for (int g = 0; g < 4; ++g)
#pragma unroll
        for (int jj = 0; jj < 2; ++jj) {
            const float send = tA[g][(1^s)*2 + jj];
            tB[g][jj] = tA[g][s*2 + jj] + __shfl_xor(send, 16);
        }
    s = (l >> 3) & 1; ib += s;
    float fg[4];
#pragma unroll
    for (int g = 0; g < 4; ++g) {
        const float send = tB[g][1^s];
        fg[g] = tB[g][s] + __shfl_xor(send, 8);
    }
#pragma unroll
    for (int mm = 4; mm >= 1; mm >>= 1)
#pragma unroll
        for (int g = 0; g < 4; ++g) fg[g] += __shfl_xor(fg[g], mm);

    if ((l & 7) == 0) {
        const int b = b0 + ib;
        const float rg = 1.f/(1.f + expf(-(fg[0] + b_ih[j]      + b_hh[j])));
        const float zg = 1.f/(1.f + expf(-(fg[1] + b_ih[HD+j]   + b_hh[HD+j])));
        const float ng = tanhf(fg[2] + b_ih[2*HD+j] + rg*(fg[3] + b_hh[2*HD+j]));
        const float hp = h_prev[(size_t)b*HD + j];
        h_next[(size_t)b*HD + j] = (1.f - zg)*ng + zg*hp;
    }
}

// ---------------------------------------------------------------------------
// 5) Logits + store + argmax. Block owns 64 vocab rows x all 32 batches.
//    h staged in 64KB LDS (2 K-chunks); coalesced W_fc stream; butterfly
//    reduce; LDS transpose for coalesced stores; 8-sharded atomicMax argmax.
// ---------------------------------------------------------------------------
__global__ void __launch_bounds__(256) k_logits(
    const float* __restrict__ h, const float* __restrict__ W_fc,
    const float* __restrict__ b_fc, float* __restrict__ out,
    ull* __restrict__ slots_cur, int tstep)
{
    __shared__ float smem[32*512];     // 64KB; reused as stage[32][65] at end
    const int t = threadIdx.x;
    const int w = t >> 6, l = t & 63;
    const int rowblk = blockIdx.x * 64;

    float ffin[4][2];
#pragma unroll
    for (int p = 0; p < 4; ++p) { ffin[p][0] = 0.f; ffin[p][1] = 0.f; }

    for (int c = 0; c < 2; ++c) {
        __syncthreads();
#pragma unroll
        for (int u = 0; u < 16; ++u) {
            const int f = t + u*256;           // f4 index 0..4095
            const int b = f >> 7;              // 128 float4 per batch
            const int k4 = (f & 127)*4;
            *(float4*)&smem[b*512 + k4] = *(const float4*)&h[(size_t)b*HD + c*512 + k4];
        }
        __syncthreads();
#pragma unroll
        for (int p = 0; p < 4; ++p) {
            const int rl0 = w*16 + p*4;
            float acc[4][32];
#pragma unroll
            for (int r = 0; r < 4; ++r)
#pragma unroll
                for (int b = 0; b < 32; ++b) acc[r][b] = 0.f;
#pragma unroll
            for (int q = 0; q < 2; ++q) {
                const int k = q*256 + l*4;
                const size_t wbase = (size_t)(rowblk + rl0)*HD + (size_t)c*512 + k;
                const float4 w0 = *(const float4*)(W_fc + wbase);
                const float4 w1 = *(const float4*)(W_fc + wbase + HD);
                const float4 w2 = *(const float4*)(W_fc + wbase + 2*HD);
                const float4 w3 = *(const float4*)(W_fc + wbase + 3*HD);
#pragma unroll
                for (int b = 0; b < 32; ++b) {
                    const float4 xv = *(const float4*)&smem[b*512 + k];
                    DOT4(acc[0][b], w0, xv);
                    DOT4(acc[1][b], w1, xv);
                    DOT4(acc[2][b], w2, xv);
                    DOT4(acc[3][b], w3, xv);
                }
            }
            // reduce acc[4][32] over 64 lanes -> 2 values per lane
            int s = (l >> 5) & 1;
            float t2[2][32];
#pragma unroll
            for (int rr = 0; rr < 2; ++rr)
#pragma unroll
                for (int b = 0; b < 32; ++b) {
                    const float send = acc[(1^s)*2 + rr][b];
                    t2[rr][b] = acc[s*2 + rr][b] + __shfl_xor(send, 32);
                }
            s = (l >> 4) & 1;
            float u1[32];
#pragma unroll
            for (int b = 0; b < 32; ++b) {
                const float send = t2[1^s][b];
                u1[b] = t2[s][b] + __shfl_xor(send, 16);
            }
            s = (l >> 3) & 1;
            float p1[16];
#pragma unroll
            for (int b = 0; b < 16; ++b) {
                const float send = u1[(1^s)*16 + b];
                p1[b] = u1[s*16 + b] + __shfl_xor(send, 8);
            }
            s = (l >> 2) & 1;
            float q1[8];
#pragma unroll
            for (int b = 0; b < 8; ++b) {
                const float send = p1[(1^s)*8 + b];
                q1[b] = p1[s*8 + b] + __shfl_xor(send, 4);
            }
            s = (l >> 1) & 1;
            float r1[4];
#pragma unroll
            for (int b = 0; b < 4; ++b) {
                const float send = q1[(1^s)*4 + b];
                r1[b] = q1[s*4 + b] + __shfl_xor(send, 2);
            }
            s = l & 1;
#pragma unroll
            for (int b = 0; b < 2; ++b) {
                const float send = r1[(1^s)*2 + b];
                ffin[p][b] += r1[s*2 + b] + __shfl_xor(send, 1);
            }
        }
    }
    __syncthreads();
    {   // stage to LDS for coalesced store: stage[b][row_local], stride 65
        const int rfin = ((l >> 5) & 1)*2 + ((l >> 4) & 1);
        const int bb = ((l >> 3) & 1)*16 + ((l >> 2) & 1)*8 + ((l >> 1) & 1)*4 + (l & 1)*2;
#pragma unroll
        for (int p = 0; p < 4; ++p) {
            const int rl = w*16 + p*4 + rfin;
            smem[(bb + 0)*65 + rl] = ffin[p][0];
            smem[(bb + 1)*65 + rl] = ffin[p][1];
        }
    }
    __syncthreads();
    {   // thread t: batch b = t>>3, rows rl0s..rl0s+7
        const int b = t >> 3;
        const int rl0s = (t & 7)*8;
        float v[8];
        ull bk = 0ull;
#pragma unroll
        for (int e = 0; e < 8; ++e) {
            const int rl = rl0s + e;
            const int rg = rowblk + rl;
            const float val = smem[b*65 + rl] + b_fc[rg];
            v[e] = val;
            const ull key = (((ull)enc_f32(val)) << 32) | (ull)(~(uint)rg);
            bk = (key > bk) ? key : bk;
        }
        float* dst = out + (size_t)b*((size_t)SEQL*VOC) + (size_t)tstep*VOC + rowblk + rl0s;
        ((float4*)dst)[0] = make_float4(v[0], v[1], v[2], v[3]);
        ((float4*)dst)[1] = make_float4(v[4], v[5], v[6], v[7]);
#pragma unroll
        for (int mm = 4; mm >= 1; mm >>= 1) {
            const ull o = shflxor64(bk, mm);
            bk = (o > bk) ? o : bk;
        }
        if ((t & 7) == 0) atomicMax(slots_cur + (blockIdx.x & 7)*NB + b, bk);
    }
}

// ---------------------------------------------------------------------------
extern "C" void kernel_launch(void* const* d_in, const int* in_sizes, int n_in,
                              void* d_out, int out_size, void* d_ws, size_t ws_size,
                              hipStream_t stream)
{
    const float* features = (const float*)d_in[0];
    const int*   captions = (const int*)d_in[1];
    // d_in[2] = max_seq_length (known: 64)
    const float* emb  = (const float*)d_in[3];
    const float* Wa1  = (const float*)d_in[4];
    const float* ba1  = (const float*)d_in[5];
    const float* Wa2  = (const float*)d_in[6];
    // d_in[7] = ba2 (zeros; softmax-invariant)
    const float* W_ih = (const float*)d_in[8];
    const float* W_hh = (const float*)d_in[9];
    const float* b_ih = (const float*)d_in[10];
    const float* b_hh = (const float*)d_in[11];
    const float* W_fc = (const float*)d_in[12];
    const float* b_fc = (const float*)d_in[13];

    float* out = (float*)d_out;
    float* A_out = out + (size_t)NB*SEQL*VOC;

    char* wsp = (char*)d_ws;
    float* combined = (float*)wsp;  wsp += (size_t)NROWS*ED*4;     // 34 MB
    float* partials = (float*)wsp;  wsp += (size_t)NROWS*16*4;
    float* hbuf0    = (float*)wsp;  wsp += (size_t)NB*HD*4;
    float* hbuf1    = (float*)wsp;  wsp += (size_t)NB*HD*4;
    float* ctx      = (float*)wsp;  wsp += (size_t)NB*HD*4;
    ull*   slots    = (ull*)wsp;    wsp += 2*8*NB*sizeof(ull);     // [2][8][32]

    k_build<<<NROWS + 1000, 256, 0, stream>>>(features, captions, emb, combined, out);
    k_attn_gemm<<<130*16, 256, 0, stream>>>(combined, Wa1, ba1, Wa2, partials);
    k_attn_finish<<<NB, 256, 0, stream>>>(partials, combined, captions,
                                          A_out, hbuf0, ctx, slots);
    for (int t = 1; t < SEQL; ++t) {
        const float* hp = (t & 1) ? hbuf0 : hbuf1;
        float*       hn = (t & 1) ? hbuf1 : hbuf0;
        const ull* sp = slots + (size_t)((t - 1) & 1)*8*NB;
        ull*       scur = slots + (size_t)(t & 1)*8*NB;
        k_gru<<<1024, 256, 0, stream>>>(emb, ctx, W_ih, W_hh, b_ih, b_hh,
                                        hp, hn, sp, scur);
        k_logits<<<VOC/64, 256, 0, stream>>>(hn, W_fc, b_fc, out, scur, t);
    }
}

// Round 2
// 6497.385 us; speedup vs baseline: 6.7405x; 6.7405x over previous
//
#include <hip/hip_runtime.h>

typedef unsigned long long ull;
typedef unsigned int uint;

#define NB 32
#define NFEAT 196
#define SEQL 64
#define ED 1024
#define HD 1024
#define VOC 32000
#define NCOMB 260                  // NFEAT + SEQL
#define NROWS (NB*NCOMB)           // 8320
#define RPB 64                     // vocab rows per k_logits block

#define DOT4(acc, wv, xv) acc = fmaf((wv).x,(xv).x, fmaf((wv).y,(xv).y, fmaf((wv).z,(xv).z, fmaf((wv).w,(xv).w,(acc)))))

__device__ __forceinline__ uint enc_f32(float f) {
    uint u = __float_as_uint(f);
    return (u & 0x80000000u) ? ~u : (u | 0x80000000u);
}
__device__ __forceinline__ ull shflxor64(ull v, int m) {
    uint lo = __shfl_xor((uint)v, m);
    uint hi = __shfl_xor((uint)(v >> 32), m);
    return (((ull)hi) << 32) | (ull)lo;
}

// ---------------------------------------------------------------------------
// 1) Build combined = [features ; emb[captions]]  (8320 x 1024) into ws,
//    and zero outputs[:, 0, :] (harness does not re-poison between replays).
// ---------------------------------------------------------------------------
__global__ void __launch_bounds__(256) k_build(
    const float* __restrict__ features, const int* __restrict__ captions,
    const float* __restrict__ emb, float* __restrict__ combined,
    float* __restrict__ out)
{
    const int bid = blockIdx.x;
    const int t = threadIdx.x;
    if (bid < NROWS) {
        const int b = bid / NCOMB;
        const int i = bid - b*NCOMB;
        const float* src = (i < NFEAT)
            ? (features + ((size_t)(b*NFEAT + i))*ED)
            : (emb + (size_t)captions[b*SEQL + (i - NFEAT)]*ED);
        float4* dst4 = (float4*)(combined + (size_t)bid*ED);
        const float4* s4 = (const float4*)src;
        dst4[t] = s4[t];
    } else {
        const int z = bid - NROWS;           // 0..999
        const int m = z*1024 + t*4;          // < 1,024,000 exactly covered
        if (m < NB*VOC) {
            const int b = m / VOC;
            const int v = m - b*VOC;
            float4 zz = make_float4(0.f,0.f,0.f,0.f);
            *(float4*)(out + (size_t)b*((size_t)SEQL*VOC) + v) = zz;
        }
    }
}

// ---------------------------------------------------------------------------
// 2) Attention GEMM: T = combined @ Wa1^T, fused tanh(+ba1)*Wa2 column
//    reduction -> deterministic per-(row, coltile) partial scores.
// ---------------------------------------------------------------------------
__global__ void __launch_bounds__(256) k_attn_gemm(
    const float* __restrict__ combined, const float* __restrict__ Wa1,
    const float* __restrict__ ba1, const float* __restrict__ Wa2,
    float* __restrict__ partials)
{
    __shared__ float cs_t[32][68];
    __shared__ float wt_t[32][68];
    __shared__ float red[64][17];
    const int bid = blockIdx.x;
    const int ct = bid & 15;          // col tile 0..15
    const int rt = bid >> 4;          // row tile 0..129
    const int t = threadIdx.x;
    const int tx = t & 15, ty = t >> 4;
    const int row0 = rt*64, col0 = ct*64;

    float acc[4][4];
#pragma unroll
    for (int i = 0; i < 4; ++i)
#pragma unroll
        for (int j = 0; j < 4; ++j) acc[i][j] = 0.f;

    for (int kc = 0; kc < ED; kc += 32) {
#pragma unroll
        for (int u = 0; u < 8; ++u) {
            const int idx = t + u*256;        // 0..2047
            const int r = idx >> 5, k = idx & 31;
            cs_t[k][r] = combined[(size_t)(row0 + r)*ED + kc + k];
            wt_t[k][r] = Wa1[(size_t)(col0 + r)*ED + kc + k];
        }
        __syncthreads();
#pragma unroll
        for (int kk = 0; kk < 32; ++kk) {
            const float4 av = *(const float4*)&cs_t[kk][ty*4];
            const float4 bv = *(const float4*)&wt_t[kk][tx*4];
            acc[0][0] = fmaf(av.x, bv.x, acc[0][0]);
            acc[0][1] = fmaf(av.x, bv.y, acc[0][1]);
            acc[0][2] = fmaf(av.x, bv.z, acc[0][2]);
            acc[0][3] = fmaf(av.x, bv.w, acc[0][3]);
            acc[1][0] = fmaf(av.y, bv.x, acc[1][0]);
            acc[1][1] = fmaf(av.y, bv.y, acc[1][1]);
            acc[1][2] = fmaf(av.y, bv.z, acc[1][2]);
            acc[1][3] = fmaf(av.y, bv.w, acc[1][3]);
            acc[2][0] = fmaf(av.z, bv.x, acc[2][0]);
            acc[2][1] = fmaf(av.z, bv.y, acc[2][1]);
            acc[2][2] = fmaf(av.z, bv.z, acc[2][2]);
            acc[2][3] = fmaf(av.z, bv.w, acc[2][3]);
            acc[3][0] = fmaf(av.w, bv.x, acc[3][0]);
            acc[3][1] = fmaf(av.w, bv.y, acc[3][1]);
            acc[3][2] = fmaf(av.w, bv.z, acc[3][2]);
            acc[3][3] = fmaf(av.w, bv.w, acc[3][3]);
        }
        __syncthreads();
    }
#pragma unroll
    for (int i = 0; i < 4; ++i) {
        float s = 0.f;
#pragma unroll
        for (int j = 0; j < 4; ++j) {
            const int c = col0 + tx*4 + j;
            s += tanhf(acc[i][j] + ba1[c]) * Wa2[c];
        }
        red[ty*4 + i][tx] = s;
    }
    __syncthreads();
    if (t < 64) {
        float s = 0.f;
#pragma unroll
        for (int x = 0; x < 16; ++x) s += red[t][x];   // fixed order: deterministic
        partials[(size_t)(row0 + t)*16 + ct] = s;
    }
}

// ---------------------------------------------------------------------------
// 3) Per-batch softmax over 260 scores -> A (output), h0 = sum A_i*combined_i,
//    init h buffer / context / argmax slot parity 0 with captions[:,0].
// ---------------------------------------------------------------------------
__global__ void __launch_bounds__(256) k_attn_finish(
    const float* __restrict__ partials, const float* __restrict__ combined,
    const int* __restrict__ captions,
    float* __restrict__ A_out, float* __restrict__ h0,
    float* __restrict__ ctx, ull* __restrict__ slots0)
{
    const int b = blockIdx.x, t = threadIdx.x;
    __shared__ float sc[NCOMB];
    __shared__ float red[256];

    for (int i = t; i < NCOMB; i += 256) {
        float s = 0.f;
        const float* pr = partials + (size_t)(b*NCOMB + i)*16;
#pragma unroll
        for (int g = 0; g < 16; ++g) s += pr[g];
        sc[i] = s;
    }
    __syncthreads();
    float m = -1e30f;
    for (int i = t; i < NCOMB; i += 256) m = fmaxf(m, sc[i]);
    red[t] = m; __syncthreads();
    for (int s2 = 128; s2 > 0; s2 >>= 1) {
        if (t < s2) red[t] = fmaxf(red[t], red[t+s2]);
        __syncthreads();
    }
    m = red[0]; __syncthreads();
    float ssum = 0.f;
    for (int i = t; i < NCOMB; i += 256) { float e = expf(sc[i] - m); sc[i] = e; ssum += e; }
    red[t] = ssum; __syncthreads();
    for (int s2 = 128; s2 > 0; s2 >>= 1) {
        if (t < s2) red[t] += red[t+s2];
        __syncthreads();
    }
    const float S = red[0]; __syncthreads();
    for (int i = t; i < NCOMB; i += 256) {
        const float a = sc[i] / S;
        sc[i] = a;
        A_out[b*NCOMB + i] = a;
    }
    __syncthreads();
    for (int e = t; e < HD; e += 256) {
        float acc = 0.f;
        const float* cb = combined + (size_t)b*NCOMB*ED + e;
        for (int i = 0; i < NCOMB; ++i) acc = fmaf(sc[i], cb[(size_t)i*ED], acc);
        h0[(size_t)b*HD + e] = acc;
        ctx[(size_t)b*HD + e] = acc;
    }
    if (t == 0) {
        slots0[0*NB + b] = (ull)(~(uint)captions[b*SEQL]);   // decodes to captions[b,0]
#pragma unroll
        for (int g = 1; g < 8; ++g) slots0[g*NB + b] = 0ull;
    }
}

// ---------------------------------------------------------------------------
// 4) GRU cell, one kernel per step. Block j owns gate triple (j, H+j, 2H+j).
// ---------------------------------------------------------------------------
__global__ void __launch_bounds__(256) k_gru(
    const float* __restrict__ emb, const float* __restrict__ ctx,
    const float* __restrict__ W_ih, const float* __restrict__ W_hh,
    const float* __restrict__ b_ih, const float* __restrict__ b_hh,
    const float* __restrict__ h_prev, float* __restrict__ h_next,
    const ull* __restrict__ slots_prev, ull* __restrict__ slots_cur)
{
    __shared__ int word_s[NB];
    const int t = threadIdx.x;
    if (t < NB) {
        ull best = 0ull;
#pragma unroll
        for (int g = 0; g < 8; ++g) {
            ull k = slots_prev[g*NB + t];
            best = (k > best) ? k : best;
        }
        word_s[t] = (int)(~(uint)best);
    }
    if (blockIdx.x == 0) slots_cur[t] = 0ull;   // 256 = 8*32 entries
    __syncthreads();

    const int j = blockIdx.x;            // 0..1023
    const int w = t >> 6, l = t & 63;
    const int b0 = w*8;

    float a[4][8];                       // 0:r(i+h) 1:z(i+h) 2:inn 3:hn
#pragma unroll
    for (int g = 0; g < 4; ++g)
#pragma unroll
        for (int i = 0; i < 8; ++i) a[g][i] = 0.f;

    const float* Wr = W_ih + (size_t)j*(ED+HD);
    const float* Wz = W_ih + (size_t)(HD + j)*(ED+HD);
    const float* Wn = W_ih + (size_t)(2*HD + j)*(ED+HD);
#pragma unroll
    for (int q = 0; q < 8; ++q) {
        const int k = q*256 + l*4;
        const float4 wr = *(const float4*)(Wr + k);
        const float4 wz = *(const float4*)(Wz + k);
        const float4 wn = *(const float4*)(Wn + k);
#pragma unroll
        for (int i = 0; i < 8; ++i) {
            const int b = b0 + i;
            const float* xs = (q < 4) ? (emb + (size_t)word_s[b]*ED + k)
                                      : (ctx + (size_t)b*HD + (k - ED));
            const float4 xv = *(const float4*)xs;
            DOT4(a[0][i], wr, xv);
            DOT4(a[1][i], wz, xv);
            DOT4(a[2][i], wn, xv);
        }
    }
    const float* Ur = W_hh + (size_t)j*HD;
    const float* Uz = W_hh + (size_t)(HD + j)*HD;
    const float* Un = W_hh + (size_t)(2*HD + j)*HD;
#pragma unroll
    for (int q = 0; q < 4; ++q) {
        const int k = q*256 + l*4;
        const float4 ur = *(const float4*)(Ur + k);
        const float4 uz = *(const float4*)(Uz + k);
        const float4 un = *(const float4*)(Un + k);
#pragma unroll
        for (int i = 0; i < 8; ++i) {
            const int b = b0 + i;
            const float4 hv = *(const float4*)(h_prev + (size_t)b*HD + k);
            DOT4(a[0][i], ur, hv);
            DOT4(a[1][i], uz, hv);
            DOT4(a[3][i], un, hv);
        }
    }
    int s = (l >> 5) & 1;
    int ib = s*4;
    float tA[4][4];
#pragma unroll
    for (int g = 0; g < 4; ++g)
#pragma unroll
        for (int ii = 0; ii < 4; ++ii) {
            const float send = a[g][(1^s)*4 + ii];
            tA[g][ii] = a[g][s*4 + ii] + __shfl_xor(send, 32);
        }
    s = (l >> 4) & 1; ib += s*2;
    float tB[4][2];
#pragma unroll
    for (int g = 0; g < 4; ++g)
#pragma unroll
        for (int jj = 0; jj < 2; ++jj) {
            const float send = tA[g][(1^s)*2 + jj];
            tB[g][jj] = tA[g][s*2 + jj] + __shfl_xor(send, 16);
        }
    s = (l >> 3) & 1; ib += s;
    float fg[4];
#pragma unroll
    for (int g = 0; g < 4; ++g) {
        const float send = tB[g][1^s];
        fg[g] = tB[g][s] + __shfl_xor(send, 8);
    }
#pragma unroll
    for (int mm = 4; mm >= 1; mm >>= 1)
#pragma unroll
        for (int g = 0; g < 4; ++g) fg[g] += __shfl_xor(fg[g], mm);

    if ((l & 7) == 0) {
        const int b = b0 + ib;
        const float rg = 1.f/(1.f + expf(-(fg[0] + b_ih[j]      + b_hh[j])));
        const float zg = 1.f/(1.f + expf(-(fg[1] + b_ih[HD+j]   + b_hh[HD+j])));
        const float ng = tanhf(fg[2] + b_ih[2*HD+j] + rg*(fg[3] + b_hh[2*HD+j]));
        const float hp = h_prev[(size_t)b*HD + j];
        h_next[(size_t)b*HD + j] = (1.f - zg)*ng + zg*hp;
    }
}

// ---------------------------------------------------------------------------
// 5) Logits + store + argmax, spill-free register tiling.
//    Block: 64 vocab rows x 32 batches, 4 waves = {row-half wr} x {K-half wk}.
//    Lane (bg=l>>3, rg=l&7) owns rows {wr*32+rg+8j} x batches {bg+8i}:
//    acc[4][4] complete dot products over its K-half -> no K butterfly.
//    W tile + transposed h tile staged in LDS per 128-k chunk; bank-safe
//    strides (Wl stride 35 f4 -> row-step bank offset 12; ht stride 33 f4 ->
//    batch-step bank offset 4). One LDS pass merges the two K-halves.
// ---------------------------------------------------------------------------
__global__ void __launch_bounds__(256) k_logits(
    const float* __restrict__ h, const float* __restrict__ W_fc,
    const float* __restrict__ b_fc, float* __restrict__ out,
    ull* __restrict__ slots_cur, int tstep)
{
    __shared__ float4 Wl[64*35];     // [row][wk*17 + k4], pad col
    __shared__ float4 htl[32*33];    // [b][kq], kq = wk*16 + k4
    __shared__ float  red[2*64*16];  // [wr][lane][j*4+i]

    const int t = threadIdx.x;
    const int w = t >> 6, l = t & 63;
    const int wk = w & 1, wr = w >> 1;
    const int bg = l >> 3, rg = l & 7;
    const int rowblk = blockIdx.x * RPB;

    float acc[4][4];
#pragma unroll
    for (int j = 0; j < 4; ++j)
#pragma unroll
        for (int i = 0; i < 4; ++i) acc[j][i] = 0.f;

    for (int c = 0; c < 8; ++c) {
        // stage W: 64 rows x 128 k = 2048 float4
#pragma unroll
        for (int u = 0; u < 8; ++u) {
            const int f = t + u*256;
            const int row = f >> 5, kq = f & 31;
            Wl[row*35 + (kq >> 4)*17 + (kq & 15)] =
                *(const float4*)&W_fc[(size_t)(rowblk + row)*HD + c*128 + kq*4];
        }
        // stage h^T: 32 b x 128 k = 1024 float4
#pragma unroll
        for (int u = 0; u < 4; ++u) {
            const int f = t + u*256;
            const int b = f >> 5, kq = f & 31;
            htl[b*33 + kq] = *(const float4*)&h[(size_t)b*HD + c*128 + kq*4];
        }
        __syncthreads();
        const float4* Wb = &Wl[(wr*32 + rg)*35 + wk*17];
        const float4* hb = &htl[bg*33 + wk*16];
#pragma unroll
        for (int k4 = 0; k4 < 16; ++k4) {
            const float4 w0 = Wb[k4];
            const float4 w1 = Wb[8*35 + k4];
            const float4 w2 = Wb[16*35 + k4];
            const float4 w3 = Wb[24*35 + k4];
            const float4 h0 = hb[k4];
            const float4 h1 = hb[8*33 + k4];
            const float4 h2 = hb[16*33 + k4];
            const float4 h3 = hb[24*33 + k4];
            DOT4(acc[0][0], w0, h0); DOT4(acc[0][1], w0, h1);
            DOT4(acc[0][2], w0, h2); DOT4(acc[0][3], w0, h3);
            DOT4(acc[1][0], w1, h0); DOT4(acc[1][1], w1, h1);
            DOT4(acc[1][2], w1, h2); DOT4(acc[1][3], w1, h3);
            DOT4(acc[2][0], w2, h0); DOT4(acc[2][1], w2, h1);
            DOT4(acc[2][2], w2, h2); DOT4(acc[2][3], w2, h3);
            DOT4(acc[3][0], w3, h0); DOT4(acc[3][1], w3, h1);
            DOT4(acc[3][2], w3, h2); DOT4(acc[3][3], w3, h3);
        }
        __syncthreads();
    }

    // merge K-halves: wk=1 writes partials, wk=0 adds + finalizes
    if (wk == 1) {
        float* rr = &red[(wr*64 + l)*16];
#pragma unroll
        for (int j = 0; j < 4; ++j)
            *(float4*)&rr[j*4] = make_float4(acc[j][0], acc[j][1], acc[j][2], acc[j][3]);
    }
    __syncthreads();
    if (wk == 0) {
        const float* rr = &red[(wr*64 + l)*16];
        ull bk[4] = {0ull, 0ull, 0ull, 0ull};
#pragma unroll
        for (int j = 0; j < 4; ++j) {
            const int rowg = rowblk + wr*32 + rg + 8*j;
            const float bias = b_fc[rowg];
#pragma unroll
            for (int i = 0; i < 4; ++i) {
                const float v = acc[j][i] + rr[j*4 + i] + bias;
                const int b = bg + 8*i;
                out[(size_t)b*((size_t)SEQL*VOC) + (size_t)tstep*VOC + rowg] = v;
                const ull key = (((ull)enc_f32(v)) << 32) | (ull)(~(uint)rowg);
                bk[i] = (key > bk[i]) ? key : bk[i];
            }
        }
#pragma unroll
        for (int mm = 1; mm <= 4; mm <<= 1)
#pragma unroll
            for (int i = 0; i < 4; ++i) {
                const ull o = shflxor64(bk[i], mm);
                bk[i] = (o > bk[i]) ? o : bk[i];
            }
        if (rg == 0) {
#pragma unroll
            for (int i = 0; i < 4; ++i)
                atomicMax(slots_cur + (blockIdx.x & 7)*NB + bg + 8*i, bk[i]);
        }
    }
}

// ---------------------------------------------------------------------------
extern "C" void kernel_launch(void* const* d_in, const int* in_sizes, int n_in,
                              void* d_out, int out_size, void* d_ws, size_t ws_size,
                              hipStream_t stream)
{
    const float* features = (const float*)d_in[0];
    const int*   captions = (const int*)d_in[1];
    // d_in[2] = max_seq_length (known: 64)
    const float* emb  = (const float*)d_in[3];
    const float* Wa1  = (const float*)d_in[4];
    const float* ba1  = (const float*)d_in[5];
    const float* Wa2  = (const float*)d_in[6];
    // d_in[7] = ba2 (zeros; softmax-invariant)
    const float* W_ih = (const float*)d_in[8];
    const float* W_hh = (const float*)d_in[9];
    const float* b_ih = (const float*)d_in[10];
    const float* b_hh = (const float*)d_in[11];
    const float* W_fc = (const float*)d_in[12];
    const float* b_fc = (const float*)d_in[13];

    float* out = (float*)d_out;
    float* A_out = out + (size_t)NB*SEQL*VOC;

    char* wsp = (char*)d_ws;
    float* combined = (float*)wsp;  wsp += (size_t)NROWS*ED*4;     // 34 MB
    float* partials = (float*)wsp;  wsp += (size_t)NROWS*16*4;
    float* hbuf0    = (float*)wsp;  wsp += (size_t)NB*HD*4;
    float* hbuf1    = (float*)wsp;  wsp += (size_t)NB*HD*4;
    float* ctx      = (float*)wsp;  wsp += (size_t)NB*HD*4;
    ull*   slots    = (ull*)wsp;    wsp += 2*8*NB*sizeof(ull);     // [2][8][32]

    k_build<<<NROWS + 1000, 256, 0, stream>>>(features, captions, emb, combined, out);
    k_attn_gemm<<<130*16, 256, 0, stream>>>(combined, Wa1, ba1, Wa2, partials);
    k_attn_finish<<<NB, 256, 0, stream>>>(partials, combined, captions,
                                          A_out, hbuf0, ctx, slots);
    for (int t = 1; t < SEQL; ++t) {
        const float* hp = (t & 1) ? hbuf0 : hbuf1;
        float*       hn = (t & 1) ? hbuf1 : hbuf0;
        const ull* sp = slots + (size_t)((t - 1) & 1)*8*NB;
        ull*       scur = slots + (size_t)(t & 1)*8*NB;
        k_gru<<<1024, 256, 0, stream>>>(emb, ctx, W_ih, W_hh, b_ih, b_hh,
                                        hp, hn, sp, scur);
        k_logits<<<VOC/RPB, 256, 0, stream>>>(hn, W_fc, b_fc, out, scur, t);
    }
}

// Round 3
// 5674.379 us; speedup vs baseline: 7.7181x; 1.1450x over previous
//
#include <hip/hip_runtime.h>
#include <hip/hip_bf16.h>

typedef unsigned long long ull;
typedef unsigned int uint;

#define NB 32
#define NFEAT 196
#define SEQL 64
#define ED 1024
#define HD 1024
#define VOC 32000
#define NCOMB 260                  // NFEAT + SEQL
#define NROWS (NB*NCOMB)           // 8320

typedef __attribute__((ext_vector_type(8))) short s16x8;   // 8 bf16 = 4 VGPRs
typedef __attribute__((ext_vector_type(4))) float f32x4;
typedef __attribute__((ext_vector_type(4))) uint  u32x4;

union FragU { u32x4 u; s16x8 s; };

#define DOT4(acc, wv, xv) acc = fmaf((wv).x,(xv).x, fmaf((wv).y,(xv).y, fmaf((wv).z,(xv).z, fmaf((wv).w,(xv).w,(acc)))))

__device__ __forceinline__ uint enc_f32(float f) {
    uint u = __float_as_uint(f);
    return (u & 0x80000000u) ? ~u : (u | 0x80000000u);
}
__device__ __forceinline__ ull shflxor64(ull v, int m) {
    uint lo = __shfl_xor((uint)v, m);
    uint hi = __shfl_xor((uint)(v >> 32), m);
    return (((ull)hi) << 32) | (ull)lo;
}

// split float pair -> (hi bf16x2 bits, lo bf16x2 bits); RTNE hi, lo = residual
__device__ __forceinline__ void split2(float a, float b, uint& hi, uint& lo) {
    __hip_bfloat162 h2 = __float22bfloat162_rn(make_float2(a, b));
    float2 hf = __bfloat1622float2(h2);
    __hip_bfloat162 l2 = __float22bfloat162_rn(make_float2(a - hf.x, b - hf.y));
    hi = *(uint*)&h2;
    lo = *(uint*)&l2;
}

// ---------------------------------------------------------------------------
// 1) Build combined = [features ; emb[captions]] and zero outputs[:, 0, :].
// ---------------------------------------------------------------------------
__global__ void __launch_bounds__(256) k_build(
    const float* __restrict__ features, const int* __restrict__ captions,
    const float* __restrict__ emb, float* __restrict__ combined,
    float* __restrict__ out)
{
    const int bid = blockIdx.x;
    const int t = threadIdx.x;
    if (bid < NROWS) {
        const int b = bid / NCOMB;
        const int i = bid - b*NCOMB;
        const float* src = (i < NFEAT)
            ? (features + ((size_t)(b*NFEAT + i))*ED)
            : (emb + (size_t)captions[b*SEQL + (i - NFEAT)]*ED);
        float4* dst4 = (float4*)(combined + (size_t)bid*ED);
        const float4* s4 = (const float4*)src;
        dst4[t] = s4[t];
    } else {
        const int z = bid - NROWS;           // 0..999
        const int m = z*1024 + t*4;
        if (m < NB*VOC) {
            const int b = m / VOC;
            const int v = m - b*VOC;
            float4 zz = make_float4(0.f,0.f,0.f,0.f);
            *(float4*)(out + (size_t)b*((size_t)SEQL*VOC) + v) = zz;
        }
    }
}

// ---------------------------------------------------------------------------
// 2) Attention GEMM (f32, unchanged this round)
// ---------------------------------------------------------------------------
__global__ void __launch_bounds__(256) k_attn_gemm(
    const float* __restrict__ combined, const float* __restrict__ Wa1,
    const float* __restrict__ ba1, const float* __restrict__ Wa2,
    float* __restrict__ partials)
{
    __shared__ float cs_t[32][68];
    __shared__ float wt_t[32][68];
    __shared__ float red[64][17];
    const int bid = blockIdx.x;
    const int ct = bid & 15;
    const int rt = bid >> 4;
    const int t = threadIdx.x;
    const int tx = t & 15, ty = t >> 4;
    const int row0 = rt*64, col0 = ct*64;

    float acc[4][4];
#pragma unroll
    for (int i = 0; i < 4; ++i)
#pragma unroll
        for (int j = 0; j < 4; ++j) acc[i][j] = 0.f;

    for (int kc = 0; kc < ED; kc += 32) {
#pragma unroll
        for (int u = 0; u < 8; ++u) {
            const int idx = t + u*256;
            const int r = idx >> 5, k = idx & 31;
            cs_t[k][r] = combined[(size_t)(row0 + r)*ED + kc + k];
            wt_t[k][r] = Wa1[(size_t)(col0 + r)*ED + kc + k];
        }
        __syncthreads();
#pragma unroll
        for (int kk = 0; kk < 32; ++kk) {
            const float4 av = *(const float4*)&cs_t[kk][ty*4];
            const float4 bv = *(const float4*)&wt_t[kk][tx*4];
            acc[0][0] = fmaf(av.x, bv.x, acc[0][0]);
            acc[0][1] = fmaf(av.x, bv.y, acc[0][1]);
            acc[0][2] = fmaf(av.x, bv.z, acc[0][2]);
            acc[0][3] = fmaf(av.x, bv.w, acc[0][3]);
            acc[1][0] = fmaf(av.y, bv.x, acc[1][0]);
            acc[1][1] = fmaf(av.y, bv.y, acc[1][1]);
            acc[1][2] = fmaf(av.y, bv.z, acc[1][2]);
            acc[1][3] = fmaf(av.y, bv.w, acc[1][3]);
            acc[2][0] = fmaf(av.z, bv.x, acc[2][0]);
            acc[2][1] = fmaf(av.z, bv.y, acc[2][1]);
            acc[2][2] = fmaf(av.z, bv.z, acc[2][2]);
            acc[2][3] = fmaf(av.z, bv.w, acc[2][3]);
            acc[3][0] = fmaf(av.w, bv.x, acc[3][0]);
            acc[3][1] = fmaf(av.w, bv.y, acc[3][1]);
            acc[3][2] = fmaf(av.w, bv.z, acc[3][2]);
            acc[3][3] = fmaf(av.w, bv.w, acc[3][3]);
        }
        __syncthreads();
    }
#pragma unroll
    for (int i = 0; i < 4; ++i) {
        float s = 0.f;
#pragma unroll
        for (int j = 0; j < 4; ++j) {
            const int c = col0 + tx*4 + j;
            s += tanhf(acc[i][j] + ba1[c]) * Wa2[c];
        }
        red[ty*4 + i][tx] = s;
    }
    __syncthreads();
    if (t < 64) {
        float s = 0.f;
#pragma unroll
        for (int x = 0; x < 16; ++x) s += red[t][x];
        partials[(size_t)(row0 + t)*16 + ct] = s;
    }
}

// ---------------------------------------------------------------------------
// 3) Softmax + h0/ctx + slot init (unchanged)
// ---------------------------------------------------------------------------
__global__ void __launch_bounds__(256) k_attn_finish(
    const float* __restrict__ partials, const float* __restrict__ combined,
    const int* __restrict__ captions,
    float* __restrict__ A_out, float* __restrict__ h0,
    float* __restrict__ ctx, ull* __restrict__ slots0)
{
    const int b = blockIdx.x, t = threadIdx.x;
    __shared__ float sc[NCOMB];
    __shared__ float red[256];

    for (int i = t; i < NCOMB; i += 256) {
        float s = 0.f;
        const float* pr = partials + (size_t)(b*NCOMB + i)*16;
#pragma unroll
        for (int g = 0; g < 16; ++g) s += pr[g];
        sc[i] = s;
    }
    __syncthreads();
    float m = -1e30f;
    for (int i = t; i < NCOMB; i += 256) m = fmaxf(m, sc[i]);
    red[t] = m; __syncthreads();
    for (int s2 = 128; s2 > 0; s2 >>= 1) {
        if (t < s2) red[t] = fmaxf(red[t], red[t+s2]);
        __syncthreads();
    }
    m = red[0]; __syncthreads();
    float ssum = 0.f;
    for (int i = t; i < NCOMB; i += 256) { float e = expf(sc[i] - m); sc[i] = e; ssum += e; }
    red[t] = ssum; __syncthreads();
    for (int s2 = 128; s2 > 0; s2 >>= 1) {
        if (t < s2) red[t] += red[t+s2];
        __syncthreads();
    }
    const float S = red[0]; __syncthreads();
    for (int i = t; i < NCOMB; i += 256) {
        const float a = sc[i] / S;
        sc[i] = a;
        A_out[b*NCOMB + i] = a;
    }
    __syncthreads();
    for (int e = t; e < HD; e += 256) {
        float acc = 0.f;
        const float* cb = combined + (size_t)b*NCOMB*ED + e;
        for (int i = 0; i < NCOMB; ++i) acc = fmaf(sc[i], cb[(size_t)i*ED], acc);
        h0[(size_t)b*HD + e] = acc;
        ctx[(size_t)b*HD + e] = acc;
    }
    if (t == 0) {
        slots0[0*NB + b] = (ull)(~(uint)captions[b*SEQL]);
#pragma unroll
        for (int g = 1; g < 8; ++g) slots0[g*NB + b] = 0ull;
    }
}

// ---------------------------------------------------------------------------
// 4) GRU cell (unchanged)
// ---------------------------------------------------------------------------
__global__ void __launch_bounds__(256) k_gru(
    const float* __restrict__ emb, const float* __restrict__ ctx,
    const float* __restrict__ W_ih, const float* __restrict__ W_hh,
    const float* __restrict__ b_ih, const float* __restrict__ b_hh,
    const float* __restrict__ h_prev, float* __restrict__ h_next,
    const ull* __restrict__ slots_prev, ull* __restrict__ slots_cur)
{
    __shared__ int word_s[NB];
    const int t = threadIdx.x;
    if (t < NB) {
        ull best = 0ull;
#pragma unroll
        for (int g = 0; g < 8; ++g) {
            ull k = slots_prev[g*NB + t];
            best = (k > best) ? k : best;
        }
        word_s[t] = (int)(~(uint)best);
    }
    if (blockIdx.x == 0) slots_cur[t] = 0ull;
    __syncthreads();

    const int j = blockIdx.x;
    const int w = t >> 6, l = t & 63;
    const int b0 = w*8;

    float a[4][8];
#pragma unroll
    for (int g = 0; g < 4; ++g)
#pragma unroll
        for (int i = 0; i < 8; ++i) a[g][i] = 0.f;

    const float* Wr = W_ih + (size_t)j*(ED+HD);
    const float* Wz = W_ih + (size_t)(HD + j)*(ED+HD);
    const float* Wn = W_ih + (size_t)(2*HD + j)*(ED+HD);
#pragma unroll
    for (int q = 0; q < 8; ++q) {
        const int k = q*256 + l*4;
        const float4 wr = *(const float4*)(Wr + k);
        const float4 wz = *(const float4*)(Wz + k);
        const float4 wn = *(const float4*)(Wn + k);
#pragma unroll
        for (int i = 0; i < 8; ++i) {
            const int b = b0 + i;
            const float* xs = (q < 4) ? (emb + (size_t)word_s[b]*ED + k)
                                      : (ctx + (size_t)b*HD + (k - ED));
            const float4 xv = *(const float4*)xs;
            DOT4(a[0][i], wr, xv);
            DOT4(a[1][i], wz, xv);
            DOT4(a[2][i], wn, xv);
        }
    }
    const float* Ur = W_hh + (size_t)j*HD;
    const float* Uz = W_hh + (size_t)(HD + j)*HD;
    const float* Un = W_hh + (size_t)(2*HD + j)*HD;
#pragma unroll
    for (int q = 0; q < 4; ++q) {
        const int k = q*256 + l*4;
        const float4 ur = *(const float4*)(Ur + k);
        const float4 uz = *(const float4*)(Uz + k);
        const float4 un = *(const float4*)(Un + k);
#pragma unroll
        for (int i = 0; i < 8; ++i) {
            const int b = b0 + i;
            const float4 hv = *(const float4*)(h_prev + (size_t)b*HD + k);
            DOT4(a[0][i], ur, hv);
            DOT4(a[1][i], uz, hv);
            DOT4(a[3][i], un, hv);
        }
    }
    int s = (l >> 5) & 1;
    int ib = s*4;
    float tA[4][4];
#pragma unroll
    for (int g = 0; g < 4; ++g)
#pragma unroll
        for (int ii = 0; ii < 4; ++ii) {
            const float send = a[g][(1^s)*4 + ii];
            tA[g][ii] = a[g][s*4 + ii] + __shfl_xor(send, 32);
        }
    s = (l >> 4) & 1; ib += s*2;
    float tB[4][2];
#pragma unroll
    for (int g = 0; g < 4; ++g)
#pragma unroll
        for (int jj = 0; jj < 2; ++jj) {
            const float send = tA[g][(1^s)*2 + jj];
            tB[g][jj] = tA[g][s*2 + jj] + __shfl_xor(send, 16);
        }
    s = (l >> 3) & 1; ib += s;
    float fg[4];
#pragma unroll
    for (int g = 0; g < 4; ++g) {
        const float send = tB[g][1^s];
        fg[g] = tB[g][s] + __shfl_xor(send, 8);
    }
#pragma unroll
    for (int mm = 4; mm >= 1; mm >>= 1)
#pragma unroll
        for (int g = 0; g < 4; ++g) fg[g] += __shfl_xor(fg[g], mm);

    if ((l & 7) == 0) {
        const int b = b0 + ib;
        const float rg = 1.f/(1.f + expf(-(fg[0] + b_ih[j]      + b_hh[j])));
        const float zg = 1.f/(1.f + expf(-(fg[1] + b_ih[HD+j]   + b_hh[HD+j])));
        const float ng = tanhf(fg[2] + b_ih[2*HD+j] + rg*(fg[3] + b_hh[2*HD+j]));
        const float hp = h_prev[(size_t)b*HD + j];
        h_next[(size_t)b*HD + j] = (1.f - zg)*ng + zg*hp;
    }
}

// ---------------------------------------------------------------------------
// 4b) Pack h (32x1024 f32) into bf16 hi/lo B-fragment layout.
//     Entry eid = (bh*32 + ks)*64 + lane, 16 B each (s16x8):
//     elem j of lane: b = bh*16 + (lane&15),
//                     k = ks*32 + (j>>2)*16 + ((lane>>4)&3)*4 + (j&3).
// ---------------------------------------------------------------------------
__global__ void __launch_bounds__(256) k_pack_h(
    const float* __restrict__ h, uint* __restrict__ Hhi, uint* __restrict__ Hlo)
{
    const int eid = blockIdx.x*256 + threadIdx.x;      // 0..4095
    const int lane = eid & 63;
    const int ks = (eid >> 6) & 31;
    const int bh = eid >> 11;
    const int b = bh*16 + (lane & 15);
    const int k0 = ks*32 + ((lane >> 4) & 3)*4;
    const float4 wa = *(const float4*)&h[(size_t)b*HD + k0];
    const float4 wb = *(const float4*)&h[(size_t)b*HD + k0 + 16];
    uint hi[4], lo[4];
    split2(wa.x, wa.y, hi[0], lo[0]);
    split2(wa.z, wa.w, hi[1], lo[1]);
    split2(wb.x, wb.y, hi[2], lo[2]);
    split2(wb.z, wb.w, hi[3], lo[3]);
    *(u32x4*)&Hhi[(size_t)eid*4] = (u32x4){hi[0], hi[1], hi[2], hi[3]};
    *(u32x4*)&Hlo[(size_t)eid*4] = (u32x4){lo[0], lo[1], lo[2], lo[3]};
}

// ---------------------------------------------------------------------------
// 5) Logits via bf16 hi/lo MFMA (16x16x32), 3-term: WhiHhi + WhiHlo + WloHhi.
//    Block = 4 waves = 2 row-tiles x 2 batch-halves; wave = 16 rows x 16 b.
//    W_fc read f32 (64B-coalesced), split in-register; h from packed bufs.
//    No LDS/syncs in K-loop. Epilogue: 4KB LDS transpose -> coalesced store
//    + sharded atomicMax argmax.
// ---------------------------------------------------------------------------
__global__ void __launch_bounds__(256) k_logits(
    const float* __restrict__ W_fc, const uint* __restrict__ Hhi,
    const uint* __restrict__ Hlo, const float* __restrict__ b_fc,
    float* __restrict__ out, ull* __restrict__ slots_cur, int tstep)
{
    __shared__ float sm[32][33];
    const int t = threadIdx.x;
    const int w = t >> 6, l = t & 63;
    const int tile = blockIdx.x*2 + (w >> 1);          // 16-row tile, 0..1999
    const int bh = w & 1;                              // batch half
    const int row = tile*16 + (l & 15);
    const int qk = (l >> 4) & 3;

    const float* Wrow = W_fc + (size_t)row*HD;
    const u32x4* hh = (const u32x4*)Hhi + (size_t)bh*2048 + l;
    const u32x4* hl = (const u32x4*)Hlo + (size_t)bh*2048 + l;

    f32x4 acc0 = {0.f, 0.f, 0.f, 0.f};
    f32x4 acc1 = {0.f, 0.f, 0.f, 0.f};

#pragma unroll 4
    for (int ks = 0; ks < 32; ++ks) {
        const int k0 = ks*32 + qk*4;
        const float4 wa = *(const float4*)(Wrow + k0);
        const float4 wb = *(const float4*)(Wrow + k0 + 16);
        FragU whi, wlo;
        uint hi0, lo0, hi1, lo1, hi2, lo2, hi3, lo3;
        split2(wa.x, wa.y, hi0, lo0);
        split2(wa.z, wa.w, hi1, lo1);
        split2(wb.x, wb.y, hi2, lo2);
        split2(wb.z, wb.w, hi3, lo3);
        whi.u = (u32x4){hi0, hi1, hi2, hi3};
        wlo.u = (u32x4){lo0, lo1, lo2, lo3};
        FragU bhi, blo;
        bhi.u = hh[ks*64];
        blo.u = hl[ks*64];
        acc0 = __builtin_amdgcn_mfma_f32_16x16x32_bf16(whi.s, bhi.s, acc0, 0, 0, 0);
        acc1 = __builtin_amdgcn_mfma_f32_16x16x32_bf16(whi.s, blo.s, acc1, 0, 0, 0);
        acc1 = __builtin_amdgcn_mfma_f32_16x16x32_bf16(wlo.s, bhi.s, acc1, 0, 0, 0);
    }

    // epilogue: D row = (l>>4)*4 + r (local), col/batch = l&15
    {
        const int bloc = bh*16 + (l & 15);
#pragma unroll
        for (int r = 0; r < 4; ++r) {
            const int rloc = (w >> 1)*16 + (l >> 4)*4 + r;
            const int rg = tile*16 + (l >> 4)*4 + r;
            sm[bloc][rloc] = acc0[r] + acc1[r] + b_fc[rg];
        }
    }
    __syncthreads();
    {
        const int b = t >> 3;                  // 0..31
        const int q = t & 7;                   // 0..7 -> 4 rows each
        const int vbase = blockIdx.x*32 + q*4;
        float v[4];
        ull bk = 0ull;
#pragma unroll
        for (int e = 0; e < 4; ++e) {
            v[e] = sm[b][q*4 + e];
            const ull key = (((ull)enc_f32(v[e])) << 32) | (ull)(~(uint)(vbase + e));
            bk = (key > bk) ? key : bk;
        }
        *(float4*)&out[(size_t)b*((size_t)SEQL*VOC) + (size_t)tstep*VOC + vbase] =
            make_float4(v[0], v[1], v[2], v[3]);
#pragma unroll
        for (int mm = 4; mm >= 1; mm >>= 1) {
            const ull o = shflxor64(bk, mm);
            bk = (o > bk) ? o : bk;
        }
        if (q == 0) atomicMax(slots_cur + (blockIdx.x & 7)*NB + b, bk);
    }
}

// ---------------------------------------------------------------------------
extern "C" void kernel_launch(void* const* d_in, const int* in_sizes, int n_in,
                              void* d_out, int out_size, void* d_ws, size_t ws_size,
                              hipStream_t stream)
{
    const float* features = (const float*)d_in[0];
    const int*   captions = (const int*)d_in[1];
    const float* emb  = (const float*)d_in[3];
    const float* Wa1  = (const float*)d_in[4];
    const float* ba1  = (const float*)d_in[5];
    const float* Wa2  = (const float*)d_in[6];
    const float* W_ih = (const float*)d_in[8];
    const float* W_hh = (const float*)d_in[9];
    const float* b_ih = (const float*)d_in[10];
    const float* b_hh = (const float*)d_in[11];
    const float* W_fc = (const float*)d_in[12];
    const float* b_fc = (const float*)d_in[13];

    float* out = (float*)d_out;
    float* A_out = out + (size_t)NB*SEQL*VOC;

    char* wsp = (char*)d_ws;
    float* combined = (float*)wsp;  wsp += (size_t)NROWS*ED*4;     // 34 MB
    float* partials = (float*)wsp;  wsp += (size_t)NROWS*16*4;
    float* hbuf0    = (float*)wsp;  wsp += (size_t)NB*HD*4;
    float* hbuf1    = (float*)wsp;  wsp += (size_t)NB*HD*4;
    float* ctx      = (float*)wsp;  wsp += (size_t)NB*HD*4;
    ull*   slots    = (ull*)wsp;    wsp += 2*8*NB*sizeof(ull);     // [2][8][32]
    uint*  Hhi      = (uint*)wsp;   wsp += (size_t)4096*16;        // 64 KB
    uint*  Hlo      = (uint*)wsp;   wsp += (size_t)4096*16;        // 64 KB

    k_build<<<NROWS + 1000, 256, 0, stream>>>(features, captions, emb, combined, out);
    k_attn_gemm<<<130*16, 256, 0, stream>>>(combined, Wa1, ba1, Wa2, partials);
    k_attn_finish<<<NB, 256, 0, stream>>>(partials, combined, captions,
                                          A_out, hbuf0, ctx, slots);
    for (int t = 1; t < SEQL; ++t) {
        const float* hp = (t & 1) ? hbuf0 : hbuf1;
        float*       hn = (t & 1) ? hbuf1 : hbuf0;
        const ull* sp = slots + (size_t)((t - 1) & 1)*8*NB;
        ull*       scur = slots + (size_t)(t & 1)*8*NB;
        k_gru<<<1024, 256, 0, stream>>>(emb, ctx, W_ih, W_hh, b_ih, b_hh,
                                        hp, hn, sp, scur);
        k_pack_h<<<16, 256, 0, stream>>>(hn, Hhi, Hlo);
        k_logits<<<1000, 256, 0, stream>>>(W_fc, Hhi, Hlo, b_fc, out, scur, t);
    }
}

// Round 4
// 5045.551 us; speedup vs baseline: 8.6800x; 1.1246x over previous
//
#include <hip/hip_runtime.h>
#include <hip/hip_bf16.h>

typedef unsigned long long ull;
typedef unsigned int uint;

#define NB 32
#define NFEAT 196
#define SEQL 64
#define ED 1024
#define HD 1024
#define VOC 32000
#define NCOMB 260                  // NFEAT + SEQL
#define NROWS (NB*NCOMB)           // 8320

typedef __attribute__((ext_vector_type(8))) short s16x8;   // 8 bf16 = 4 VGPRs
typedef __attribute__((ext_vector_type(4))) float f32x4;
typedef __attribute__((ext_vector_type(4))) uint  u32x4;

union FragU { u32x4 u; s16x8 s; };

#define DOT4(acc, wv, xv) acc = fmaf((wv).x,(xv).x, fmaf((wv).y,(xv).y, fmaf((wv).z,(xv).z, fmaf((wv).w,(xv).w,(acc)))))

__device__ __forceinline__ uint enc_f32(float f) {
    uint u = __float_as_uint(f);
    return (u & 0x80000000u) ? ~u : (u | 0x80000000u);
}
__device__ __forceinline__ ull shflxor64(ull v, int m) {
    uint lo = __shfl_xor((uint)v, m);
    uint hi = __shfl_xor((uint)(v >> 32), m);
    return (((ull)hi) << 32) | (ull)lo;
}

// split float pair -> (hi bf16x2 bits, lo bf16x2 bits); RTNE hi, lo = residual
__device__ __forceinline__ void split2(float a, float b, uint& hi, uint& lo) {
    __hip_bfloat162 h2 = __float22bfloat162_rn(make_float2(a, b));
    float2 hf = __bfloat1622float2(h2);
    __hip_bfloat162 l2 = __float22bfloat162_rn(make_float2(a - hf.x, b - hf.y));
    hi = *(uint*)&h2;
    lo = *(uint*)&l2;
}

// ---------------------------------------------------------------------------
// 1) Build combined = [features ; emb[captions]] and zero outputs[:, 0, :].
// ---------------------------------------------------------------------------
__global__ void __launch_bounds__(256) k_build(
    const float* __restrict__ features, const int* __restrict__ captions,
    const float* __restrict__ emb, float* __restrict__ combined,
    float* __restrict__ out)
{
    const int bid = blockIdx.x;
    const int t = threadIdx.x;
    if (bid < NROWS) {
        const int b = bid / NCOMB;
        const int i = bid - b*NCOMB;
        const float* src = (i < NFEAT)
            ? (features + ((size_t)(b*NFEAT + i))*ED)
            : (emb + (size_t)captions[b*SEQL + (i - NFEAT)]*ED);
        float4* dst4 = (float4*)(combined + (size_t)bid*ED);
        const float4* s4 = (const float4*)src;
        dst4[t] = s4[t];
    } else {
        const int z = bid - NROWS;           // 0..999
        const int m = z*1024 + t*4;
        if (m < NB*VOC) {
            const int b = m / VOC;
            const int v = m - b*VOC;
            float4 zz = make_float4(0.f,0.f,0.f,0.f);
            *(float4*)(out + (size_t)b*((size_t)SEQL*VOC) + v) = zz;
        }
    }
}

// ---------------------------------------------------------------------------
// 1b) Pack Wa1 (1024x1024 f32) into hi/lo bf16 B-fragments.
//     Entry e = (ct*32 + ks)*64 + lane: col = ct*16 + (lane&15),
//     k = ks*32 + ((lane>>4)&3)*4 + (j&3) + 16*(j>>2).
// ---------------------------------------------------------------------------
__global__ void __launch_bounds__(256) k_pack_w1(
    const float* __restrict__ Wa1, uint* __restrict__ W1hi, uint* __restrict__ W1lo)
{
    const int eid = blockIdx.x*256 + threadIdx.x;      // 0..131071
    const int lane = eid & 63;
    const int ks = (eid >> 6) & 31;
    const int ct = eid >> 11;                          // 0..63
    const int c = ct*16 + (lane & 15);
    const int k0 = ks*32 + ((lane >> 4) & 3)*4;
    const float4 wa = *(const float4*)&Wa1[(size_t)c*ED + k0];
    const float4 wb = *(const float4*)&Wa1[(size_t)c*ED + k0 + 16];
    uint hi[4], lo[4];
    split2(wa.x, wa.y, hi[0], lo[0]);
    split2(wa.z, wa.w, hi[1], lo[1]);
    split2(wb.x, wb.y, hi[2], lo[2]);
    split2(wb.z, wb.w, hi[3], lo[3]);
    *(u32x4*)&W1hi[(size_t)eid*4] = (u32x4){hi[0], hi[1], hi[2], hi[3]};
    *(u32x4*)&W1lo[(size_t)eid*4] = (u32x4){lo[0], lo[1], lo[2], lo[3]};
}

// ---------------------------------------------------------------------------
// 2) Attention GEMM via MFMA hi/lo 3-term. Wave = 16 comb-rows x 64 cols
//    (4 col-tiles), A = combined streamed f32 + in-register split, B = packed
//    Wa1 fragments. Epilogue: tanh(+ba1)*Wa2, 16-lane shuffle row-reduce ->
//    partials[row][cg]. Grid (130, 16), no LDS, no barriers.
// ---------------------------------------------------------------------------
__global__ void __launch_bounds__(256) k_attn_mfma(
    const float* __restrict__ combined, const uint* __restrict__ W1hi,
    const uint* __restrict__ W1lo, const float* __restrict__ ba1,
    const float* __restrict__ Wa2, float* __restrict__ partials)
{
    const int t = threadIdx.x;
    const int w = t >> 6, l = t & 63;
    const int lane16 = l & 15, qk = (l >> 4) & 3;
    const int rt = blockIdx.x*4 + w;          // row tile 0..519
    const int cg = blockIdx.y;                // col group 0..15

    const float* Arow = combined + (size_t)(rt*16 + lane16)*ED;
    const u32x4* bh_base = (const u32x4*)W1hi + (size_t)(cg*4)*32*64 + l;
    const u32x4* bl_base = (const u32x4*)W1lo + (size_t)(cg*4)*32*64 + l;

    f32x4 acc[4];
#pragma unroll
    for (int i = 0; i < 4; ++i) acc[i] = (f32x4){0.f,0.f,0.f,0.f};

#pragma unroll 2
    for (int ks = 0; ks < 32; ++ks) {
        const int k0 = ks*32 + qk*4;
        const float4 aa = *(const float4*)(Arow + k0);
        const float4 ab = *(const float4*)(Arow + k0 + 16);
        FragU ahi, alo;
        uint h0,l0_,h1,l1_,h2,l2_,h3,l3_;
        split2(aa.x, aa.y, h0, l0_);
        split2(aa.z, aa.w, h1, l1_);
        split2(ab.x, ab.y, h2, l2_);
        split2(ab.z, ab.w, h3, l3_);
        ahi.u = (u32x4){h0, h1, h2, h3};
        alo.u = (u32x4){l0_, l1_, l2_, l3_};
#pragma unroll
        for (int i = 0; i < 4; ++i) {
            FragU bh_, bl_;
            bh_.u = bh_base[((size_t)i*32 + ks)*64];
            bl_.u = bl_base[((size_t)i*32 + ks)*64];
            acc[i] = __builtin_amdgcn_mfma_f32_16x16x32_bf16(ahi.s, bh_.s, acc[i], 0, 0, 0);
            acc[i] = __builtin_amdgcn_mfma_f32_16x16x32_bf16(ahi.s, bl_.s, acc[i], 0, 0, 0);
            acc[i] = __builtin_amdgcn_mfma_f32_16x16x32_bf16(alo.s, bh_.s, acc[i], 0, 0, 0);
        }
    }

    // epilogue: row r (local) = qk*4 + r, col = cg*64 + i*16 + lane16
    float s[4];
#pragma unroll
    for (int r = 0; r < 4; ++r) {
        float sum = 0.f;
#pragma unroll
        for (int i = 0; i < 4; ++i) {
            const int col = cg*64 + i*16 + lane16;
            sum += tanhf(acc[i][r] + ba1[col]) * Wa2[col];
        }
        s[r] = sum;
    }
#pragma unroll
    for (int m = 1; m <= 8; m <<= 1)
#pragma unroll
        for (int r = 0; r < 4; ++r) s[r] += __shfl_xor(s[r], m);
    if (lane16 == 0) {
#pragma unroll
        for (int r = 0; r < 4; ++r)
            partials[(size_t)(rt*16 + qk*4 + r)*16 + cg] = s[r];
    }
}

// ---------------------------------------------------------------------------
// 3) Softmax + h0/ctx + slot init (unchanged)
// ---------------------------------------------------------------------------
__global__ void __launch_bounds__(256) k_attn_finish(
    const float* __restrict__ partials, const float* __restrict__ combined,
    const int* __restrict__ captions,
    float* __restrict__ A_out, float* __restrict__ h0,
    float* __restrict__ ctx, ull* __restrict__ slots0)
{
    const int b = blockIdx.x, t = threadIdx.x;
    __shared__ float sc[NCOMB];
    __shared__ float red[256];

    for (int i = t; i < NCOMB; i += 256) {
        float s = 0.f;
        const float* pr = partials + (size_t)(b*NCOMB + i)*16;
#pragma unroll
        for (int g = 0; g < 16; ++g) s += pr[g];
        sc[i] = s;
    }
    __syncthreads();
    float m = -1e30f;
    for (int i = t; i < NCOMB; i += 256) m = fmaxf(m, sc[i]);
    red[t] = m; __syncthreads();
    for (int s2 = 128; s2 > 0; s2 >>= 1) {
        if (t < s2) red[t] = fmaxf(red[t], red[t+s2]);
        __syncthreads();
    }
    m = red[0]; __syncthreads();
    float ssum = 0.f;
    for (int i = t; i < NCOMB; i += 256) { float e = expf(sc[i] - m); sc[i] = e; ssum += e; }
    red[t] = ssum; __syncthreads();
    for (int s2 = 128; s2 > 0; s2 >>= 1) {
        if (t < s2) red[t] += red[t+s2];
        __syncthreads();
    }
    const float S = red[0]; __syncthreads();
    for (int i = t; i < NCOMB; i += 256) {
        const float a = sc[i] / S;
        sc[i] = a;
        A_out[b*NCOMB + i] = a;
    }
    __syncthreads();
    for (int e = t; e < HD; e += 256) {
        float acc = 0.f;
        const float* cb = combined + (size_t)b*NCOMB*ED + e;
        for (int i = 0; i < NCOMB; ++i) acc = fmaf(sc[i], cb[(size_t)i*ED], acc);
        h0[(size_t)b*HD + e] = acc;
        ctx[(size_t)b*HD + e] = acc;
    }
    if (t == 0) {
        slots0[0*NB + b] = (ull)(~(uint)captions[b*SEQL]);
#pragma unroll
        for (int g = 1; g < 8; ++g) slots0[g*NB + b] = 0ull;
    }
}

// ---------------------------------------------------------------------------
// 4) GRU cell + fused h hi/lo fragment pack (scattered 2B stores by the 32
//    holder lanes). Block j owns gate triple (j, H+j, 2H+j).
// ---------------------------------------------------------------------------
__global__ void __launch_bounds__(256) k_gru(
    const float* __restrict__ emb, const float* __restrict__ ctx,
    const float* __restrict__ W_ih, const float* __restrict__ W_hh,
    const float* __restrict__ b_ih, const float* __restrict__ b_hh,
    const float* __restrict__ h_prev, float* __restrict__ h_next,
    const ull* __restrict__ slots_prev, ull* __restrict__ slots_cur,
    uint* __restrict__ Hhi, uint* __restrict__ Hlo)
{
    __shared__ int word_s[NB];
    const int t = threadIdx.x;
    if (t < NB) {
        ull best = 0ull;
#pragma unroll
        for (int g = 0; g < 8; ++g) {
            ull k = slots_prev[g*NB + t];
            best = (k > best) ? k : best;
        }
        word_s[t] = (int)(~(uint)best);
    }
    if (blockIdx.x == 0) slots_cur[t] = 0ull;
    __syncthreads();

    const int j = blockIdx.x;
    const int w = t >> 6, l = t & 63;
    const int b0 = w*8;

    float a[4][8];
#pragma unroll
    for (int g = 0; g < 4; ++g)
#pragma unroll
        for (int i = 0; i < 8; ++i) a[g][i] = 0.f;

    const float* Wr = W_ih + (size_t)j*(ED+HD);
    const float* Wz = W_ih + (size_t)(HD + j)*(ED+HD);
    const float* Wn = W_ih + (size_t)(2*HD + j)*(ED+HD);
#pragma unroll
    for (int q = 0; q < 8; ++q) {
        const int k = q*256 + l*4;
        const float4 wr = *(const float4*)(Wr + k);
        const float4 wz = *(const float4*)(Wz + k);
        const float4 wn = *(const float4*)(Wn + k);
#pragma unroll
        for (int i = 0; i < 8; ++i) {
            const int b = b0 + i;
            const float* xs = (q < 4) ? (emb + (size_t)word_s[b]*ED + k)
                                      : (ctx + (size_t)b*HD + (k - ED));
            const float4 xv = *(const float4*)xs;
            DOT4(a[0][i], wr, xv);
            DOT4(a[1][i], wz, xv);
            DOT4(a[2][i], wn, xv);
        }
    }
    const float* Ur = W_hh + (size_t)j*HD;
    const float* Uz = W_hh + (size_t)(HD + j)*HD;
    const float* Un = W_hh + (size_t)(2*HD + j)*HD;
#pragma unroll
    for (int q = 0; q < 4; ++q) {
        const int k = q*256 + l*4;
        const float4 ur = *(const float4*)(Ur + k);
        const float4 uz = *(const float4*)(Uz + k);
        const float4 un = *(const float4*)(Un + k);
#pragma unroll
        for (int i = 0; i < 8; ++i) {
            const int b = b0 + i;
            const float4 hv = *(const float4*)(h_prev + (size_t)b*HD + k);
            DOT4(a[0][i], ur, hv);
            DOT4(a[1][i], uz, hv);
            DOT4(a[3][i], un, hv);
        }
    }
    int s = (l >> 5) & 1;
    int ib = s*4;
    float tA[4][4];
#pragma unroll
    for (int g = 0; g < 4; ++g)
#pragma unroll
        for (int ii = 0; ii < 4; ++ii) {
            const float send = a[g][(1^s)*4 + ii];
            tA[g][ii] = a[g][s*4 + ii] + __shfl_xor(send, 32);
        }
    s = (l >> 4) & 1; ib += s*2;
    float tB[4][2];
#pragma unroll
    for (int g = 0; g < 4; ++g)
#pragma unroll
        for (int jj = 0; jj < 2; ++jj) {
            const float send = tA[g][(1^s)*2 + jj];
            tB[g][jj] = tA[g][s*2 + jj] + __shfl_xor(send, 16);
        }
    s = (l >> 3) & 1; ib += s;
    float fg[4];
#pragma unroll
    for (int g = 0; g < 4; ++g) {
        const float send = tB[g][1^s];
        fg[g] = tB[g][s] + __shfl_xor(send, 8);
    }
#pragma unroll
    for (int mm = 4; mm >= 1; mm >>= 1)
#pragma unroll
        for (int g = 0; g < 4; ++g) fg[g] += __shfl_xor(fg[g], mm);

    if ((l & 7) == 0) {
        const int b = b0 + ib;
        const float rg = 1.f/(1.f + expf(-(fg[0] + b_ih[j]      + b_hh[j])));
        const float zg = 1.f/(1.f + expf(-(fg[1] + b_ih[HD+j]   + b_hh[HD+j])));
        const float ng = tanhf(fg[2] + b_ih[2*HD+j] + rg*(fg[3] + b_hh[2*HD+j]));
        const float hp = h_prev[(size_t)b*HD + j];
        const float hv = (1.f - zg)*ng + zg*hp;
        h_next[(size_t)b*HD + j] = hv;
        // fused pack into fragment layout (hi/lo bf16)
        __hip_bfloat16 hb = __float2bfloat16(hv);
        const float hf = __bfloat162float(hb);
        __hip_bfloat16 lb = __float2bfloat16(hv - hf);
        const int bh = b >> 4;
        const int ks = j >> 5;
        const int qk = (j >> 2) & 3;
        const int elem = (j & 3) + 4*((j >> 4) & 1);
        const size_t ei = (((size_t)(bh*32 + ks))*64 + qk*16 + (b & 15))*8 + elem;
        ((ushort*)Hhi)[ei] = *(const ushort*)&hb;
        ((ushort*)Hlo)[ei] = *(const ushort*)&lb;
    }
}

// ---------------------------------------------------------------------------
// 5) Logits MFMA, full-batch waves: wave = 16 vocab rows x 32 batches
//    (both halves), W_fc streamed f32 ONCE per step + in-register split.
//    Grid 500 x 4 waves. Epilogue: LDS transpose -> coalesced store + argmax.
// ---------------------------------------------------------------------------
__global__ void __launch_bounds__(256) k_logits(
    const float* __restrict__ W_fc, const uint* __restrict__ Hhi,
    const uint* __restrict__ Hlo, const float* __restrict__ b_fc,
    float* __restrict__ out, ull* __restrict__ slots_cur, int tstep)
{
    __shared__ float sm[32][68];
    const int t = threadIdx.x;
    const int w = t >> 6, l = t & 63;
    const int lane16 = l & 15, qk = (l >> 4) & 3;
    const int tile = blockIdx.x*4 + w;                 // 0..1999
    const int row = tile*16 + lane16;

    const float* Wrow = W_fc + (size_t)row*HD;
    const u32x4* hh0 = (const u32x4*)Hhi + l;
    const u32x4* hl0 = (const u32x4*)Hlo + l;
    const u32x4* hh1 = (const u32x4*)Hhi + 2048 + l;
    const u32x4* hl1 = (const u32x4*)Hlo + 2048 + l;

    f32x4 acc0 = {0.f,0.f,0.f,0.f};
    f32x4 acc1 = {0.f,0.f,0.f,0.f};

#pragma unroll 2
    for (int ks = 0; ks < 32; ++ks) {
        const int k0 = ks*32 + qk*4;
        const float4 wa = *(const float4*)(Wrow + k0);
        const float4 wb = *(const float4*)(Wrow + k0 + 16);
        FragU whi, wlo;
        uint h0,l0_,h1,l1_,h2,l2_,h3,l3_;
        split2(wa.x, wa.y, h0, l0_);
        split2(wa.z, wa.w, h1, l1_);
        split2(wb.x, wb.y, h2, l2_);
        split2(wb.z, wb.w, h3, l3_);
        whi.u = (u32x4){h0, h1, h2, h3};
        wlo.u = (u32x4){l0_, l1_, l2_, l3_};
        FragU b0h, b0l, b1h, b1l;
        b0h.u = hh0[ks*64];
        b0l.u = hl0[ks*64];
        b1h.u = hh1[ks*64];
        b1l.u = hl1[ks*64];
        acc0 = __builtin_amdgcn_mfma_f32_16x16x32_bf16(whi.s, b0h.s, acc0, 0, 0, 0);
        acc0 = __builtin_amdgcn_mfma_f32_16x16x32_bf16(whi.s, b0l.s, acc0, 0, 0, 0);
        acc0 = __builtin_amdgcn_mfma_f32_16x16x32_bf16(wlo.s, b0h.s, acc0, 0, 0, 0);
        acc1 = __builtin_amdgcn_mfma_f32_16x16x32_bf16(whi.s, b1h.s, acc1, 0, 0, 0);
        acc1 = __builtin_amdgcn_mfma_f32_16x16x32_bf16(whi.s, b1l.s, acc1, 0, 0, 0);
        acc1 = __builtin_amdgcn_mfma_f32_16x16x32_bf16(wlo.s, b1h.s, acc1, 0, 0, 0);
    }

    // D: row_local = w*16 + qk*4 + r, col(batch) = bh*16 + lane16
    {
        const int rbase = w*16 + qk*4;
        const float4 bias = *(const float4*)&b_fc[blockIdx.x*64 + rbase];
        *(float4*)&sm[lane16][rbase] = make_float4(
            acc0[0] + bias.x, acc0[1] + bias.y, acc0[2] + bias.z, acc0[3] + bias.w);
        *(float4*)&sm[16 + lane16][rbase] = make_float4(
            acc1[0] + bias.x, acc1[1] + bias.y, acc1[2] + bias.z, acc1[3] + bias.w);
    }
    __syncthreads();
    {
        const int b = t >> 3;                  // 0..31
        const int rl0 = (t & 7)*8;
        const int vbase = blockIdx.x*64 + rl0;
        float v[8];
        ull bk = 0ull;
#pragma unroll
        for (int e = 0; e < 8; ++e) {
            v[e] = sm[b][rl0 + e];
            const ull key = (((ull)enc_f32(v[e])) << 32) | (ull)(~(uint)(vbase + e));
            bk = (key > bk) ? key : bk;
        }
        float* dst = out + (size_t)b*((size_t)SEQL*VOC) + (size_t)tstep*VOC + vbase;
        ((float4*)dst)[0] = make_float4(v[0], v[1], v[2], v[3]);
        ((float4*)dst)[1] = make_float4(v[4], v[5], v[6], v[7]);
#pragma unroll
        for (int mm = 4; mm >= 1; mm >>= 1) {
            const ull o = shflxor64(bk, mm);
            bk = (o > bk) ? o : bk;
        }
        if ((t & 7) == 0) atomicMax(slots_cur + (blockIdx.x & 7)*NB + b, bk);
    }
}

// ---------------------------------------------------------------------------
extern "C" void kernel_launch(void* const* d_in, const int* in_sizes, int n_in,
                              void* d_out, int out_size, void* d_ws, size_t ws_size,
                              hipStream_t stream)
{
    const float* features = (const float*)d_in[0];
    const int*   captions = (const int*)d_in[1];
    const float* emb  = (const float*)d_in[3];
    const float* Wa1  = (const float*)d_in[4];
    const float* ba1  = (const float*)d_in[5];
    const float* Wa2  = (const float*)d_in[6];
    const float* W_ih = (const float*)d_in[8];
    const float* W_hh = (const float*)d_in[9];
    const float* b_ih = (const float*)d_in[10];
    const float* b_hh = (const float*)d_in[11];
    const float* W_fc = (const float*)d_in[12];
    const float* b_fc = (const float*)d_in[13];

    float* out = (float*)d_out;
    float* A_out = out + (size_t)NB*SEQL*VOC;

    char* wsp = (char*)d_ws;
    float* combined = (float*)wsp;  wsp += (size_t)NROWS*ED*4;     // 34 MB
    float* partials = (float*)wsp;  wsp += (size_t)NROWS*16*4;
    float* hbuf0    = (float*)wsp;  wsp += (size_t)NB*HD*4;
    float* hbuf1    = (float*)wsp;  wsp += (size_t)NB*HD*4;
    float* ctx      = (float*)wsp;  wsp += (size_t)NB*HD*4;
    ull*   slots    = (ull*)wsp;    wsp += 2*8*NB*sizeof(ull);     // [2][8][32]
    uint*  Hhi      = (uint*)wsp;   wsp += (size_t)4096*16;        // 64 KB
    uint*  Hlo      = (uint*)wsp;   wsp += (size_t)4096*16;        // 64 KB
    uint*  W1hi     = (uint*)wsp;   wsp += (size_t)131072*16;      // 2 MB
    uint*  W1lo     = (uint*)wsp;   wsp += (size_t)131072*16;      // 2 MB

    k_build<<<NROWS + 1000, 256, 0, stream>>>(features, captions, emb, combined, out);
    k_pack_w1<<<512, 256, 0, stream>>>(Wa1, W1hi, W1lo);
    k_attn_mfma<<<dim3(130, 16), 256, 0, stream>>>(combined, W1hi, W1lo, ba1, Wa2, partials);
    k_attn_finish<<<NB, 256, 0, stream>>>(partials, combined, captions,
                                          A_out, hbuf0, ctx, slots);
    for (int t = 1; t < SEQL; ++t) {
        const float* hp = (t & 1) ? hbuf0 : hbuf1;
        float*       hn = (t & 1) ? hbuf1 : hbuf0;
        const ull* sp = slots + (size_t)((t - 1) & 1)*8*NB;
        ull*       scur = slots + (size_t)(t & 1)*8*NB;
        k_gru<<<1024, 256, 0, stream>>>(emb, ctx, W_ih, W_hh, b_ih, b_hh,
                                        hp, hn, sp, scur, Hhi, Hlo);
        k_logits<<<500, 256, 0, stream>>>(W_fc, Hhi, Hlo, b_fc, out, scur, t);
    }
}